// Round 1
// baseline (644.499 us; speedup 1.0000x reference)
//
#include <hip/hip_runtime.h>
#include <cstdint>
#include <cstddef>

typedef unsigned short u16;
typedef short short8 __attribute__((ext_vector_type(8)));
typedef float f32x4 __attribute__((ext_vector_type(4)));

#define B_   2
#define T_   2048
#define H_   16
#define HID_ 2048
#define DQK_ 192
#define DV_  128

__device__ __forceinline__ float bf2f(u16 u) {
  unsigned int v = ((unsigned int)u) << 16;
  return __builtin_bit_cast(float, v);
}
__device__ __forceinline__ u16 f2bf(float f) {
  unsigned int u = __builtin_bit_cast(unsigned int, f);
  u += 0x7fff + ((u >> 16) & 1);   // round-to-nearest-even
  return (u16)(u >> 16);
}
__device__ __forceinline__ void load_lds16(const void* g, void* l) {
  __builtin_amdgcn_global_load_lds((const __attribute__((address_space(1))) void*)g,
                                   (__attribute__((address_space(3))) void*)l, 16, 0, 0);
}

// ---------------- cast f32 -> bf16 (8 elems/thread) ----------------
__global__ __launch_bounds__(256) void cast_f32_bf16(const float* __restrict__ x,
                                                     u16* __restrict__ y) {
  size_t i = ((size_t)blockIdx.x * 256 + threadIdx.x) * 8;
  float4 a = *(const float4*)&x[i];
  float4 b = *(const float4*)&x[i + 4];
  u16 r[8];
  r[0] = f2bf(a.x); r[1] = f2bf(a.y); r[2] = f2bf(a.z); r[3] = f2bf(a.w);
  r[4] = f2bf(b.x); r[5] = f2bf(b.y); r[6] = f2bf(b.z); r[7] = f2bf(b.w);
  *(uint4*)&y[i] = *(const uint4*)&r[0];
}

// ---------------- W (K x N) f32  ->  Wt (N x K) bf16 ----------------
__global__ __launch_bounds__(256) void transpose_cast_k(const float* __restrict__ W,
                                                        u16* __restrict__ Wt,
                                                        int K, int N) {
  __shared__ u16 tile[32][33];
  int n0 = blockIdx.x * 32, k0 = blockIdx.y * 32;
  int tx = threadIdx.x & 31, ty = threadIdx.x >> 5;
#pragma unroll
  for (int i = 0; i < 32; i += 8)
    tile[ty + i][tx] = f2bf(W[(size_t)(k0 + ty + i) * N + n0 + tx]);
  __syncthreads();
#pragma unroll
  for (int i = 0; i < 32; i += 8)
    Wt[(size_t)(n0 + ty + i) * K + k0 + tx] = tile[tx][ty + i];
}

// ---------------- RMSNorm over rows (bf16 in/out, f32 weight) ----------------
__global__ __launch_bounds__(256) void rmsnorm_k(const u16* __restrict__ in, int in_stride,
                                                 int L, const float* __restrict__ w,
                                                 u16* __restrict__ out, int out_stride) {
  int row = blockIdx.x;
  const u16* x = in + (size_t)row * in_stride;
  float ss = 0.f;
  for (int i = threadIdx.x * 8; i < L; i += 2048) {
    uint4 v = *(const uint4*)&x[i];
    const u16* p = (const u16*)&v;
#pragma unroll
    for (int e = 0; e < 8; ++e) { float f = bf2f(p[e]); ss += f * f; }
  }
#pragma unroll
  for (int m = 32; m >= 1; m >>= 1) ss += __shfl_xor(ss, m);
  __shared__ float red[4];
  if ((threadIdx.x & 63) == 0) red[threadIdx.x >> 6] = ss;
  __syncthreads();
  ss = red[0] + red[1] + red[2] + red[3];
  float inv = rsqrtf(ss / (float)L + 1e-6f);
  u16* o = out + (size_t)row * out_stride;
  for (int i = threadIdx.x * 8; i < L; i += 2048) {
    uint4 v = *(const uint4*)&x[i];
    const u16* p = (const u16*)&v;
    u16 r8[8];
#pragma unroll
    for (int e = 0; e < 8; ++e) r8[e] = f2bf(bf2f(p[e]) * inv * w[i + e]);
    *(uint4*)&o[i] = *(const uint4*)&r8[0];
  }
}

// ---------------- GEMM: A(MxK) bf16 row-major, Bt(NxK) bf16, C(MxN) ----------------
// m97 structure: 128x128 tile, BK=32, 4 waves (2x2), each 64x64 (4x4 16x16 frags)
template <int STORE_BF16>
__global__ __launch_bounds__(256) void gemm_bt(const u16* __restrict__ A,
                                               const u16* __restrict__ Bt,
                                               void* __restrict__ Cout,
                                               int M, int N, int K) {
  __shared__ u16 As[128 * 32];
  __shared__ u16 Bs[128 * 32];
  const int nbx = N >> 7;
  const int bx = blockIdx.x % nbx, by = blockIdx.x / nbx;
  const int m0 = by << 7, n0 = bx << 7;
  const int tid = threadIdx.x, w = tid >> 6, lane = tid & 63;
  const int wr = w >> 1, wc = w & 1;
  const int llo = lane & 15, lhi = lane >> 4;
  f32x4 acc[4][4] = {};
  const u16* Ag = A + (size_t)(m0 + w * 32 + (lane >> 2)) * K + (lane & 3) * 8;
  const u16* Bg = Bt + (size_t)(n0 + w * 32 + (lane >> 2)) * K + (lane & 3) * 8;
  u16* Al = &As[(w * 32 + (lane >> 2)) * 32 + (lane & 3) * 8];
  u16* Bl = &Bs[(w * 32 + (lane >> 2)) * 32 + (lane & 3) * 8];
  for (int k0 = 0; k0 < K; k0 += 32) {
    load_lds16(Ag + k0, Al);
    load_lds16(Ag + k0 + (size_t)16 * K, Al + 16 * 32);
    load_lds16(Bg + k0, Bl);
    load_lds16(Bg + k0 + (size_t)16 * K, Bl + 16 * 32);
    __syncthreads();
    short8 af[4], bfr[4];
#pragma unroll
    for (int i = 0; i < 4; ++i)
      af[i] = *(const short8*)&As[(wr * 64 + i * 16 + llo) * 32 + lhi * 8];
#pragma unroll
    for (int j = 0; j < 4; ++j)
      bfr[j] = *(const short8*)&Bs[(wc * 64 + j * 16 + llo) * 32 + lhi * 8];
#pragma unroll
    for (int i = 0; i < 4; ++i)
#pragma unroll
      for (int j = 0; j < 4; ++j)
        acc[i][j] = __builtin_amdgcn_mfma_f32_16x16x32_bf16(af[i], bfr[j], acc[i][j], 0, 0, 0);
    __syncthreads();
  }
  if constexpr (STORE_BF16) {
    u16* C = (u16*)Cout;
#pragma unroll
    for (int i = 0; i < 4; ++i)
#pragma unroll
      for (int j = 0; j < 4; ++j)
#pragma unroll
        for (int r = 0; r < 4; ++r)
          C[(size_t)(m0 + wr * 64 + i * 16 + lhi * 4 + r) * N + (n0 + wc * 64 + j * 16 + llo)] =
              f2bf(acc[i][j][r]);
  } else {
    float* C = (float*)Cout;
#pragma unroll
    for (int i = 0; i < 4; ++i)
#pragma unroll
      for (int j = 0; j < 4; ++j)
#pragma unroll
        for (int r = 0; r < 4; ++r)
          C[(size_t)(m0 + wr * 64 + i * 16 + lhi * 4 + r) * N + (n0 + wc * 64 + j * 16 + llo)] =
              acc[i][j][r];
  }
}

// ---------------- repacks ----------------
// q (B*T, H*192) -> Qp (B,H,T,192)
__global__ __launch_bounds__(256) void pack_q_k(const u16* __restrict__ q, u16* __restrict__ Qp) {
  size_t i = (size_t)blockIdx.x * 256 + threadIdx.x;   // 16B-chunk index
  int c = (int)(i % 24);
  size_t r = i / 24;
  int t = (int)(r % T_);
  int bh = (int)(r / T_);
  int h = bh & 15, b = bh >> 4;
  uint4 v = *(const uint4*)&q[((size_t)(b * T_ + t)) * (H_ * DQK_) + h * DQK_ + c * 8];
  *(uint4*)&Qp[i * 8] = v;
}
// K = concat(k_nope from kv, k_rope from kvraw) -> Kp (B,H,T,192)
__global__ __launch_bounds__(256) void pack_k_k(const u16* __restrict__ kv,
                                                const u16* __restrict__ kvraw,
                                                u16* __restrict__ Kp) {
  size_t i = (size_t)blockIdx.x * 256 + threadIdx.x;
  int c = (int)(i % 24);
  size_t r = i / 24;
  int t = (int)(r % T_);
  int bh = (int)(r / T_);
  int h = bh & 15, b = bh >> 4;
  uint4 v;
  if (c < 16)
    v = *(const uint4*)&kv[((size_t)(b * T_ + t)) * 4096 + h * 256 + c * 8];
  else
    v = *(const uint4*)&kvraw[((size_t)(b * T_ + t)) * 1536 + 512 + h * 64 + (c - 16) * 8];
  *(uint4*)&Kp[i * 8] = v;
}
// V (from kv cols 128..255 per head) -> Vt (B,H,128,T)  (transposed for PV B-operand)
__global__ __launch_bounds__(256) void pack_vt_k(const u16* __restrict__ kv, u16* __restrict__ Vt) {
  __shared__ u16 tile[64][136];
  const int nt = T_ / 64;  // 32
  int t0 = (blockIdx.x % nt) * 64;
  int bh = blockIdx.x / nt;
  int b = bh >> 4, h = bh & 15;
  int row = threadIdx.x >> 4;     // 0..15
  int ck = threadIdx.x & 15;      // 16 chunks of 8 = 128 dims
#pragma unroll
  for (int i = 0; i < 64; i += 16) {
    uint4 v = *(const uint4*)&kv[((size_t)(b * T_) + t0 + row + i) * 4096 + h * 256 + 128 + ck * 8];
    *(uint4*)&tile[row + i][ck * 8] = v;
  }
  __syncthreads();
  int d = threadIdx.x >> 1;
  int th = (threadIdx.x & 1) * 32;
  u16 tmp[32];
#pragma unroll
  for (int e = 0; e < 32; ++e) tmp[e] = tile[th + e][d];
#pragma unroll
  for (int e = 0; e < 32; e += 8)
    *(uint4*)&Vt[((size_t)bh * 128 + d) * T_ + t0 + th + e] = *(const uint4*)&tmp[e];
}

// ---------------- causal flash attention ----------------
// block = 256 thr (4 waves). Q-tile 128 rows (wave w owns 32). K-tile 64.
// Qp/Kp: (B,H,T,192), Vt: (B,H,128,T). out attn: (B,T,H*128) bf16.
__global__ __launch_bounds__(256, 2) void attn_k(const u16* __restrict__ Qp,
                                                 const u16* __restrict__ Kp,
                                                 const u16* __restrict__ Vt,
                                                 u16* __restrict__ attn) {
  constexpr int KLD = 200, VLD = 72, PLD = 72;  // padded strides (bank offset 4)
  __shared__ u16 Ks[64 * KLD];
  __shared__ u16 Vs[128 * VLD];
  __shared__ u16 Ps[128 * PLD];
  const int nqt = 16;
  const int qt = (nqt - 1) - ((int)blockIdx.x % nqt);  // longest blocks first
  const int bh = blockIdx.x / nqt;
  const int b = bh >> 4, h = bh & 15;
  const int q0 = qt * 128;
  const u16* Qb = Qp + (size_t)bh * T_ * DQK_;
  const u16* Kb = Kp + (size_t)bh * T_ * DQK_;
  const u16* Vb = Vt + (size_t)bh * DV_ * T_;
  const int tid = threadIdx.x, w = tid >> 6, lane = tid & 63;
  const int llo = lane & 15, lhi = lane >> 4;
  short8 qf[2][6];
#pragma unroll
  for (int i = 0; i < 2; ++i)
#pragma unroll
    for (int kk = 0; kk < 6; ++kk)
      qf[i][kk] = *(const short8*)&Qb[(size_t)(q0 + w * 32 + i * 16 + llo) * DQK_ + kk * 32 + lhi * 8];
  f32x4 oacc[2][8] = {};
  float m_r[2][4], l_r[2][4];
#pragma unroll
  for (int i = 0; i < 2; ++i)
#pragma unroll
    for (int r = 0; r < 4; ++r) { m_r[i][r] = -1e30f; l_r[i][r] = 0.f; }
  const float scale = 0.07216878364870323f;  // 1/sqrt(192)
  const int nkt = 2 * qt + 2;
  for (int kt = 0; kt < nkt; ++kt) {
    const int k0 = kt * 64;
    uint4 kreg[6], vreg[4];
    const u16* Ksrc = Kb + (size_t)k0 * DQK_;
#pragma unroll
    for (int ii = 0; ii < 6; ++ii) kreg[ii] = *(const uint4*)&Ksrc[(ii * 256 + tid) * 8];
#pragma unroll
    for (int ii = 0; ii < 4; ++ii) {
      int c = ii * 256 + tid;
      vreg[ii] = *(const uint4*)&Vb[(size_t)(c >> 3) * T_ + k0 + (c & 7) * 8];
    }
    __syncthreads();  // all waves done reading previous Ks/Vs
#pragma unroll
    for (int ii = 0; ii < 6; ++ii) {
      int f = (ii * 256 + tid) * 8;
      int rr = f / 192, cc = f - rr * 192;
      *(uint4*)&Ks[rr * KLD + cc] = kreg[ii];
    }
#pragma unroll
    for (int ii = 0; ii < 4; ++ii) {
      int c = ii * 256 + tid;
      *(uint4*)&Vs[(c >> 3) * VLD + (c & 7) * 8] = vreg[ii];
    }
    __syncthreads();  // tiles staged
    // S = Q K^T
    f32x4 s[2][4] = {};
#pragma unroll
    for (int kk = 0; kk < 6; ++kk) {
      short8 kf[4];
#pragma unroll
      for (int j = 0; j < 4; ++j)
        kf[j] = *(const short8*)&Ks[(j * 16 + llo) * KLD + kk * 32 + lhi * 8];
#pragma unroll
      for (int i = 0; i < 2; ++i)
#pragma unroll
        for (int j = 0; j < 4; ++j)
          s[i][j] = __builtin_amdgcn_mfma_f32_16x16x32_bf16(qf[i][kk], kf[j], s[i][j], 0, 0, 0);
    }
    // online softmax (rows owned per-lane: row = i*16 + lhi*4 + r, col = j*16 + llo)
#pragma unroll
    for (int i = 0; i < 2; ++i) {
#pragma unroll
      for (int r = 0; r < 4; ++r) {
        const int qrow = q0 + w * 32 + i * 16 + lhi * 4 + r;
        float sv[4];
#pragma unroll
        for (int j = 0; j < 4; ++j) {
          int kcol = k0 + j * 16 + llo;
          float x = s[i][j][r] * scale;
          sv[j] = (kcol <= qrow) ? x : -1e30f;
        }
        float mx = fmaxf(fmaxf(sv[0], sv[1]), fmaxf(sv[2], sv[3]));
#pragma unroll
        for (int mk = 1; mk < 16; mk <<= 1) mx = fmaxf(mx, __shfl_xor(mx, mk));
        float mold = m_r[i][r];
        float mnew = fmaxf(mold, mx);
        float alpha = __expf(mold - mnew);
        float rs = 0.f;
#pragma unroll
        for (int j = 0; j < 4; ++j) {
          float p = __expf(sv[j] - mnew);
          rs += p;
          Ps[(w * 32 + i * 16 + lhi * 4 + r) * PLD + j * 16 + llo] = f2bf(p);
        }
#pragma unroll
        for (int mk = 1; mk < 16; mk <<= 1) rs += __shfl_xor(rs, mk);
        l_r[i][r] = l_r[i][r] * alpha + rs;
        m_r[i][r] = mnew;
#pragma unroll
        for (int jo = 0; jo < 8; ++jo) oacc[i][jo][r] *= alpha;
      }
    }
    // PV (wave-local P region; same-wave LDS RAW ordered by lgkmcnt)
#pragma unroll
    for (int kk2 = 0; kk2 < 2; ++kk2) {
      short8 pf[2];
#pragma unroll
      for (int i = 0; i < 2; ++i)
        pf[i] = *(const short8*)&Ps[(w * 32 + i * 16 + llo) * PLD + kk2 * 32 + lhi * 8];
#pragma unroll
      for (int jo = 0; jo < 8; ++jo) {
        short8 vf = *(const short8*)&Vs[(jo * 16 + llo) * VLD + kk2 * 32 + lhi * 8];
#pragma unroll
        for (int i = 0; i < 2; ++i)
          oacc[i][jo] = __builtin_amdgcn_mfma_f32_16x16x32_bf16(pf[i], vf, oacc[i][jo], 0, 0, 0);
      }
    }
  }
  // epilogue: attn[b, t, h*128 + d]
#pragma unroll
  for (int i = 0; i < 2; ++i)
#pragma unroll
    for (int r = 0; r < 4; ++r) {
      const int qrow = q0 + w * 32 + i * 16 + lhi * 4 + r;
      float linv = 1.f / l_r[i][r];
#pragma unroll
      for (int jo = 0; jo < 8; ++jo)
        attn[((size_t)(b * T_) + qrow) * (H_ * DV_) + h * DV_ + jo * 16 + llo] =
            f2bf(oacc[i][jo][r] * linv);
    }
}

// ---------------- launch ----------------
extern "C" void kernel_launch(void* const* d_in, const int* in_sizes, int n_in,
                              void* d_out, int out_size, void* d_ws, size_t ws_size,
                              hipStream_t stream) {
  const float* hs      = (const float*)d_in[0];
  const float* q_a_w   = (const float*)d_in[1];
  const float* q_a_ln  = (const float*)d_in[2];
  const float* q_b_w   = (const float*)d_in[3];
  const float* kv_a_w  = (const float*)d_in[4];
  const float* kv_a_ln = (const float*)d_in[5];
  const float* kv_b_w  = (const float*)d_in[6];
  const float* o_w     = (const float*)d_in[7];
  float* out = (float*)d_out;
  char* ws = (char*)d_ws;

  u16* hid = (u16*)(ws + 0);          // 16.78 MB  (B*T, HID) bf16
  u16* wt  = (u16*)(ws + 16777216);   //  9.44 MB  transposed weight (reused)
  u16* qa  = (u16*)(ws + 26214400);   // 12.58 MB  q_a / later kv_raw
  u16* qan = (u16*)(ws + 38797312);   // 12.58 MB  q_a normed / later kv_latent
  u16* q   = (u16*)(ws + 51380224);   // 25.17 MB  q / later attn out
  u16* kv  = (u16*)(ws + 76546048);   // 33.55 MB  kv_b output
  u16* Qp  = (u16*)(ws + 110100480);  // 25.17 MB
  u16* Kp  = (u16*)(ws + 135266304);  // 25.17 MB
  u16* Vt  = (u16*)(ws + 160432128);  // 16.78 MB   (total ~177 MB)

  cast_f32_bf16<<<4096, 256, 0, stream>>>(hs, hid);

  // q_a = hidden @ q_a_w ; rmsnorm
  transpose_cast_k<<<dim3(1536 / 32, 2048 / 32), 256, 0, stream>>>(q_a_w, wt, 2048, 1536);
  gemm_bt<1><<<(1536 / 128) * (4096 / 128), 256, 0, stream>>>(hid, wt, qa, 4096, 1536, 2048);
  rmsnorm_k<<<4096, 256, 0, stream>>>(qa, 1536, 1536, q_a_ln, qan, 1536);

  // q = q_a_n @ q_b_w
  transpose_cast_k<<<dim3(3072 / 32, 1536 / 32), 256, 0, stream>>>(q_b_w, wt, 1536, 3072);
  gemm_bt<1><<<(3072 / 128) * (4096 / 128), 256, 0, stream>>>(qan, wt, q, 4096, 3072, 1536);

  // kv_raw = hidden @ kv_a_w ; rmsnorm latent
  transpose_cast_k<<<dim3(1536 / 32, 2048 / 32), 256, 0, stream>>>(kv_a_w, wt, 2048, 1536);
  gemm_bt<1><<<(1536 / 128) * (4096 / 128), 256, 0, stream>>>(hid, wt, qa, 4096, 1536, 2048);
  rmsnorm_k<<<4096, 256, 0, stream>>>(qa, 1536, 512, kv_a_ln, qan, 512);

  // kv = kv_latent @ kv_b_w
  transpose_cast_k<<<dim3(4096 / 32, 512 / 32), 256, 0, stream>>>(kv_b_w, wt, 512, 4096);
  gemm_bt<1><<<(4096 / 128) * (4096 / 128), 256, 0, stream>>>(qan, wt, kv, 4096, 4096, 512);

  // repack Q/K/V
  pack_q_k<<<6144, 256, 0, stream>>>(q, Qp);
  pack_k_k<<<6144, 256, 0, stream>>>(kv, qa, Kp);
  pack_vt_k<<<1024, 256, 0, stream>>>(kv, Vt);

  // attention -> attn (aliases q)
  attn_k<<<512, 256, 0, stream>>>(Qp, Kp, Vt, q);

  // out = attn @ o_w
  transpose_cast_k<<<dim3(2048 / 32, 2048 / 32), 256, 0, stream>>>(o_w, wt, 2048, 2048);
  gemm_bt<0><<<(2048 / 128) * (4096 / 128), 256, 0, stream>>>(q, wt, out, 4096, 2048, 2048);
}